// Round 1
// 624.951 us; speedup vs baseline: 1.3355x; 1.3355x over previous
//
#include <hip/hip_runtime.h>
#include <hip/hip_bf16.h>

typedef __bf16 bf16x8 __attribute__((ext_vector_type(8)));
typedef float  f32x4  __attribute__((ext_vector_type(4)));

#define B_   16
#define CIN  64
#define COUT 64
#define H_   256
#define W_   256
#define TY   16
#define SLOT (258 * 64)

// ---------------- Kernel 1: modulate + demodulate weights -> bf16 [b][tap][co][ci]
__global__ void modw_kernel(const float* __restrict__ weight,
                            const float* __restrict__ y,
                            __bf16* __restrict__ w1g) {
  const int co = blockIdx.x;
  const int b  = blockIdx.y;
  const int ci = threadIdx.x;               // 64 threads = 1 wave
  const float c  = 0.041666666666666664f;   // (64*9)^-0.5 = 1/24
  const float yv = y[b*CIN + ci] * c;
  float w[9];
  float s = 0.0f;
#pragma unroll
  for (int t = 0; t < 9; ++t) {
    float wv = weight[(co*CIN + ci)*9 + t] * yv;
    w[t] = wv;
    s += wv * wv;
  }
#pragma unroll
  for (int off = 32; off > 0; off >>= 1) s += __shfl_xor(s, off, 64);
  const float d = rsqrtf(s + 1e-8f);
#pragma unroll
  for (int t = 0; t < 9; ++t)
    w1g[((b*9 + t)*COUT + co)*CIN + ci] = (__bf16)(w[t] * d);
}

// ---------------- staging helpers: one thread = 8 ci (group cg) x 4 px
__device__ __forceinline__ void stage_load(const float* __restrict__ X,
                                           int b, int yy, int tid, float4* f) {
  const int cg = tid >> 6;
  const int px_base = 4 * (tid & 63);
  const float* xrow = X + ((long)b * (CIN * H_ * W_) + (long)yy * W_);
#pragma unroll
  for (int j = 0; j < 8; ++j)
    f[j] = *reinterpret_cast<const float4*>(xrow + (long)(cg * 8 + j) * (H_ * W_) + px_base);
}

__device__ __forceinline__ void stage_write(__bf16* __restrict__ xs, int slot,
                                            int tid, const float4* f, bool valid) {
  const int cg = tid >> 6;
  const int px_base = 4 * (tid & 63);
  bf16x8 frag[4];
  if (valid) {
#pragma unroll
    for (int j = 0; j < 8; ++j) {
      frag[0][j] = (__bf16)f[j].x;
      frag[1][j] = (__bf16)f[j].y;
      frag[2][j] = (__bf16)f[j].z;
      frag[3][j] = (__bf16)f[j].w;
    }
  } else {
#pragma unroll
    for (int o = 0; o < 4; ++o)
#pragma unroll
      for (int j = 0; j < 8; ++j) frag[o][j] = (__bf16)0.f;
  }
#pragma unroll
  for (int oo = 0; oo < 4; ++oo) {
    const int o  = (oo + tid) & 3;            // rotate to spread write banks
    const int pl = px_base + o + 1;           // px_lds (cols 0 / 257 are zero pads)
    const int gs = cg ^ (pl & 7);             // XOR bank swizzle
    *reinterpret_cast<bf16x8*>(&xs[slot * SLOT + pl * 64 + gs * 8]) = frag[o];
  }
}

// ---------------- Kernel 2: strip-mined implicit-GEMM conv.
// One block per (b, 16-row strip). Rolling 3-slot row buffer in LDS.
// 8 waves = 2 co-halves x 4 px-quarters; each wave: 2 co-tiles x 4 px-tiles.
// Pipeline per row: S1 -> issue global loads for row y+2 -> MFMA row y -> S2
// -> store row y -> convert+ds_write row y+2 (slot freed by S2).
__global__ __launch_bounds__(512)
void conv_kernel(const float* __restrict__ X,
                 const __bf16* __restrict__ w1g,
                 float* __restrict__ out) {
  const int y0   = blockIdx.x * TY;
  const int b    = blockIdx.y;
  const int tid  = threadIdx.x;
  const int lane = tid & 63;
  const int wv   = tid >> 6;        // wave 0..7
  const int cgw  = wv & 1;          // co half (32 co)
  const int pg   = wv >> 1;         // px quarter (64 px)
  const int q    = lane >> 4;       // 0..3
  const int n    = lane & 15;       // 0..15

  __shared__ __bf16 xs[3 * SLOT];   // 99 KB: 3 row slots [258][64] bf16, swizzled

  // zero the pad columns (px_lds = 0 and 257) of all 3 slots, once
  if (tid < 384) {
    const int s = tid >> 7, r = tid & 127;
    const int col = (r < 64) ? 0 : 257;
    xs[s * SLOT + col * 64 + (r & 63)] = (__bf16)0.f;
  }

  // prologue: stage rows y0-1, y0, y0+1 (y0+1 <= 241 always valid)
  {
    float4 f[8];
#pragma unroll
    for (int k = 0; k < 3; ++k) {
      const int yy = y0 - 1 + k;
      const bool valid = (yy >= 0);
      if (valid) stage_load(X, b, yy, tid, f);
      stage_write(xs, (yy + 3) % 3, tid, f, valid);
    }
  }

  float4 pf[8];                     // prefetch registers for row y+2
  for (int ty = 0; ty < TY; ++ty) {
    const int y = y0 + ty;
    __syncthreads();                               // S1: staged rows visible

    const int yy = y + 2;
    const bool do_pf = (ty < TY - 1);              // row y0+16 is the last needed
    const bool pf_ok = do_pf && (yy < H_);
    if (pf_ok) stage_load(X, b, yy, tid, pf);      // issue loads; land during MFMA

    f32x4 acc[2][4];
#pragma unroll
    for (int c2 = 0; c2 < 2; ++c2)
#pragma unroll
      for (int nt = 0; nt < 4; ++nt) acc[c2][nt] = (f32x4){0.f, 0.f, 0.f, 0.f};

#pragma unroll
    for (int dy = 0; dy < 3; ++dy) {
      const __bf16* sl = &xs[((y - 1 + dy + 3) % 3) * SLOT];

      // A fragments for this dy's 3 taps (2 co-tiles, 2 K-halves) — L2-resident
      bf16x8 afr[2][3][2];
#pragma unroll
      for (int c2 = 0; c2 < 2; ++c2) {
        const int co = cgw * 32 + c2 * 16 + n;
#pragma unroll
        for (int dx = 0; dx < 3; ++dx) {
          const int tap = dy * 3 + dx;
          const __bf16* wp = w1g + ((b * 9 + tap) * COUT + co) * CIN + q * 8;
          afr[c2][dx][0] = *reinterpret_cast<const bf16x8*>(wp);        // ci = q*8+j
          afr[c2][dx][1] = *reinterpret_cast<const bf16x8*>(wp + 32);   // ci = 32+q*8+j
        }
      }

#pragma unroll
      for (int dx = 0; dx < 3; ++dx) {
        const int p3 = (n + dx) & 7;               // px&7 (pg*64, nt*16 = 0 mod 8)
        const int o0 = (q ^ p3) * 8;
        const int o1 = ((q + 4) ^ p3) * 8;
#pragma unroll
        for (int nt = 0; nt < 4; ++nt) {
          const int px = pg * 64 + nt * 16 + n + dx;
          const bf16x8 b0 = *reinterpret_cast<const bf16x8*>(&sl[px * 64 + o0]);
          const bf16x8 b1 = *reinterpret_cast<const bf16x8*>(&sl[px * 64 + o1]);
          acc[0][nt] = __builtin_amdgcn_mfma_f32_16x16x32_bf16(afr[0][dx][0], b0, acc[0][nt], 0, 0, 0);
          acc[0][nt] = __builtin_amdgcn_mfma_f32_16x16x32_bf16(afr[0][dx][1], b1, acc[0][nt], 0, 0, 0);
          acc[1][nt] = __builtin_amdgcn_mfma_f32_16x16x32_bf16(afr[1][dx][0], b0, acc[1][nt], 0, 0, 0);
          acc[1][nt] = __builtin_amdgcn_mfma_f32_16x16x32_bf16(afr[1][dx][1], b1, acc[1][nt], 0, 0, 0);
        }
      }
    }
    __syncthreads();                               // S2: frees slot (y-1)%3; pf landed

    // epilogue: C/D layout col=lane&15 (px), row=(lane>>4)*4+r (co)
#pragma unroll
    for (int c2 = 0; c2 < 2; ++c2) {
#pragma unroll
      for (int r = 0; r < 4; ++r) {
        const int co = cgw * 32 + c2 * 16 + q * 4 + r;
        float* op = out + ((long)(b * COUT + co) * H_ + y) * W_ + pg * 64 + n;
#pragma unroll
        for (int nt = 0; nt < 4; ++nt) op[nt * 16] = acc[c2][nt][r];
      }
    }

    // write prefetched row y+2 into slot freed by S2; visible after next S1
    if (do_pf) stage_write(xs, yy % 3, tid, pf, pf_ok);
  }
}

extern "C" void kernel_launch(void* const* d_in, const int* in_sizes, int n_in,
                              void* d_out, int out_size, void* d_ws, size_t ws_size,
                              hipStream_t stream) {
  const float* X = (const float*)d_in[0];   // (16, 64, 256, 256) fp32
  const float* y = (const float*)d_in[1];   // (16, 64) fp32
  const float* w = (const float*)d_in[2];   // (64, 64, 3, 3) fp32
  float* outp = (float*)d_out;              // (16, 64, 256, 256) fp32
  __bf16* w1g = (__bf16*)d_ws;              // 16*9*64*64 bf16 = 1.13 MB scratch

  modw_kernel<<<dim3(COUT, B_), 64, 0, stream>>>(w, y, w1g);
  conv_kernel<<<dim3(H_ / TY, B_), 512, 0, stream>>>(X, w1g, outp);
}

// Round 4
// 606.058 us; speedup vs baseline: 1.3772x; 1.0312x over previous
//
#include <hip/hip_runtime.h>
#include <hip/hip_bf16.h>

typedef __bf16 bf16x8 __attribute__((ext_vector_type(8)));
typedef float  f32x4  __attribute__((ext_vector_type(4)));

#define B_   16
#define CIN  64
#define COUT 64
#define H_   256
#define W_   256
#define TY   16
#define SLOT (258 * 64)

// ---------------- Kernel 1: modulate + demodulate weights -> bf16 [b][tap][co][ci]
__global__ void modw_kernel(const float* __restrict__ weight,
                            const float* __restrict__ y,
                            __bf16* __restrict__ w1g) {
  const int co = blockIdx.x;
  const int b  = blockIdx.y;
  const int ci = threadIdx.x;               // 64 threads = 1 wave
  const float c  = 0.041666666666666664f;   // (64*9)^-0.5 = 1/24
  const float yv = y[b*CIN + ci] * c;
  float w[9];
  float s = 0.0f;
#pragma unroll
  for (int t = 0; t < 9; ++t) {
    float wv = weight[(co*CIN + ci)*9 + t] * yv;
    w[t] = wv;
    s += wv * wv;
  }
#pragma unroll
  for (int off = 32; off > 0; off >>= 1) s += __shfl_xor(s, off, 64);
  const float d = rsqrtf(s + 1e-8f);
#pragma unroll
  for (int t = 0; t < 9; ++t)
    w1g[((b*9 + t)*COUT + co)*CIN + ci] = (__bf16)(w[t] * d);
}

// ---------------- staging helpers: one thread = 8 ci (group cg) x 4 px
__device__ __forceinline__ void stage_load(const float* __restrict__ X,
                                           int b, int yy, int tid, float4* f) {
  const int cg = tid >> 6;
  const int px_base = 4 * (tid & 63);
  const float* xrow = X + ((long)b * (CIN * H_ * W_) + (long)yy * W_);
#pragma unroll
  for (int j = 0; j < 8; ++j)
    f[j] = *reinterpret_cast<const float4*>(xrow + (long)(cg * 8 + j) * (H_ * W_) + px_base);
}

__device__ __forceinline__ void stage_write(__bf16* __restrict__ xs, int slot,
                                            int tid, const float4* f, bool valid) {
  const int cg = tid >> 6;
  const int px_base = 4 * (tid & 63);
  bf16x8 frag[4];
  if (valid) {
#pragma unroll
    for (int j = 0; j < 8; ++j) {
      frag[0][j] = (__bf16)f[j].x;
      frag[1][j] = (__bf16)f[j].y;
      frag[2][j] = (__bf16)f[j].z;
      frag[3][j] = (__bf16)f[j].w;
    }
  } else {
#pragma unroll
    for (int o = 0; o < 4; ++o)
#pragma unroll
      for (int j = 0; j < 8; ++j) frag[o][j] = (__bf16)0.f;
  }
#pragma unroll
  for (int oo = 0; oo < 4; ++oo) {
    const int o  = (oo + tid) & 3;            // rotate to spread write banks
    const int pl = px_base + o + 1;           // px_lds (cols 0 / 257 are zero pads)
    const int gs = cg ^ (pl & 7);             // XOR bank swizzle
    *reinterpret_cast<bf16x8*>(&xs[slot * SLOT + pl * 64 + gs * 8]) = frag[o];
  }
}

// ---------------- Kernel 2: strip-mined implicit-GEMM conv.
// One block per (b, 16-row strip). Rolling 3-slot row buffer in LDS.
// 8 waves = 2 co-halves x 4 px-quarters; each wave: 2 co-tiles x 4 px-tiles.
// MFMA operands: A = X fragment (M = px), B = weight fragment (N = co), so
// D[row=px][col=co]: lane holds 4 CONSECUTIVE px at one co -> dwordx4 stores.
// Weight fragments for all 9 taps are ty-invariant: hoisted into registers.
__global__ __launch_bounds__(512, 2)
void conv_kernel(const float* __restrict__ X,
                 const __bf16* __restrict__ w1g,
                 float* __restrict__ out) {
  const int y0   = blockIdx.x * TY;
  const int b    = blockIdx.y;
  const int tid  = threadIdx.x;
  const int lane = tid & 63;
  const int wv   = tid >> 6;        // wave 0..7
  const int cgw  = wv & 1;          // co half (32 co)
  const int pg   = wv >> 1;         // px quarter (64 px)
  const int q    = lane >> 4;       // 0..3
  const int n    = lane & 15;       // 0..15

  __shared__ __bf16 xs[3 * SLOT];   // 99 KB: 3 row slots [258][64] bf16, swizzled

  // zero the pad columns (px_lds = 0 and 257) of all 3 slots, once
  if (tid < 384) {
    const int s = tid >> 7, r = tid & 127;
    const int col = (r < 64) ? 0 : 257;
    xs[s * SLOT + col * 64 + (r & 63)] = (__bf16)0.f;
  }

  // hoisted weight fragments: B-operand, col = co = n, k = ci = q*8+j (+32 for ks=1)
  bf16x8 wfr[2][9][2];
#pragma unroll
  for (int c2 = 0; c2 < 2; ++c2) {
    const int co = cgw * 32 + c2 * 16 + n;
#pragma unroll
    for (int tap = 0; tap < 9; ++tap) {
      const __bf16* wp = w1g + ((b * 9 + tap) * COUT + co) * CIN + q * 8;
      wfr[c2][tap][0] = *reinterpret_cast<const bf16x8*>(wp);        // ci = q*8+j
      wfr[c2][tap][1] = *reinterpret_cast<const bf16x8*>(wp + 32);   // ci = 32+q*8+j
    }
  }

  // prologue: stage rows y0-1, y0, y0+1 (y0+1 <= 241 always valid)
  {
    float4 f[8];
#pragma unroll
    for (int k = 0; k < 3; ++k) {
      const int yy = y0 - 1 + k;
      const bool valid = (yy >= 0);
      if (valid) stage_load(X, b, yy, tid, f);
      stage_write(xs, (yy + 3) % 3, tid, f, valid);
    }
  }

  float4 pf[8];                     // prefetch registers for row y+2
  for (int ty = 0; ty < TY; ++ty) {
    const int y = y0 + ty;
    __syncthreads();                               // S1: staged rows visible

    const int yy = y + 2;
    const bool do_pf = (ty < TY - 1);              // row y0+16 is the last needed
    const bool pf_ok = do_pf && (yy < H_);
    if (pf_ok) stage_load(X, b, yy, tid, pf);      // issue loads; land during MFMA

    f32x4 acc[2][4];
#pragma unroll
    for (int c2 = 0; c2 < 2; ++c2)
#pragma unroll
      for (int nt = 0; nt < 4; ++nt) acc[c2][nt] = (f32x4){0.f, 0.f, 0.f, 0.f};

#pragma unroll
    for (int dy = 0; dy < 3; ++dy) {
      const __bf16* sl = &xs[((y - 1 + dy + 3) % 3) * SLOT];
#pragma unroll
      for (int dx = 0; dx < 3; ++dx) {
        const int tap = dy * 3 + dx;
        const int p3 = (n + dx) & 7;               // px&7 (pg*64, nt*16 = 0 mod 8)
        const int o0 = (q ^ p3) * 8;
        const int o1 = ((q + 4) ^ p3) * 8;
#pragma unroll
        for (int nt = 0; nt < 4; ++nt) {
          const int px = pg * 64 + nt * 16 + n + dx;
          const bf16x8 a0 = *reinterpret_cast<const bf16x8*>(&sl[px * 64 + o0]);
          const bf16x8 a1 = *reinterpret_cast<const bf16x8*>(&sl[px * 64 + o1]);
          acc[0][nt] = __builtin_amdgcn_mfma_f32_16x16x32_bf16(a0, wfr[0][tap][0], acc[0][nt], 0, 0, 0);
          acc[0][nt] = __builtin_amdgcn_mfma_f32_16x16x32_bf16(a1, wfr[0][tap][1], acc[0][nt], 0, 0, 0);
          acc[1][nt] = __builtin_amdgcn_mfma_f32_16x16x32_bf16(a0, wfr[1][tap][0], acc[1][nt], 0, 0, 0);
          acc[1][nt] = __builtin_amdgcn_mfma_f32_16x16x32_bf16(a1, wfr[1][tap][1], acc[1][nt], 0, 0, 0);
        }
      }
    }
    __syncthreads();                               // S2: frees slot (y-1)%3; pf landed

    // epilogue: D[row=px][col=co]: lane (q,n) holds px = q*4+r at co-offset n
#pragma unroll
    for (int c2 = 0; c2 < 2; ++c2) {
      const int co = cgw * 32 + c2 * 16 + n;
#pragma unroll
      for (int nt = 0; nt < 4; ++nt) {
        const int px0 = pg * 64 + nt * 16 + q * 4;
        *reinterpret_cast<float4*>(out + ((long)(b * COUT + co) * H_ + y) * W_ + px0) =
            *reinterpret_cast<const float4*>(&acc[c2][nt]);
      }
    }

    // write prefetched row y+2 into slot freed by S2; visible after next S1
    if (do_pf) stage_write(xs, yy % 3, tid, pf, pf_ok);
  }
}

extern "C" void kernel_launch(void* const* d_in, const int* in_sizes, int n_in,
                              void* d_out, int out_size, void* d_ws, size_t ws_size,
                              hipStream_t stream) {
  const float* X = (const float*)d_in[0];   // (16, 64, 256, 256) fp32
  const float* y = (const float*)d_in[1];   // (16, 64) fp32
  const float* w = (const float*)d_in[2];   // (64, 64, 3, 3) fp32
  float* outp = (float*)d_out;              // (16, 64, 256, 256) fp32
  __bf16* w1g = (__bf16*)d_ws;              // 16*9*64*64 bf16 = 1.13 MB scratch

  modw_kernel<<<dim3(COUT, B_), 64, 0, stream>>>(w, y, w1g);
  conv_kernel<<<dim3(H_ / TY, B_), 512, 0, stream>>>(X, w1g, outp);
}